// Round 1
// baseline (704.249 us; speedup 1.0000x reference)
//
#include <hip/hip_runtime.h>
#include <math.h>

#define NN 50000
#define NE 800000
#define ET (NE + NN)
#define HD 64
#define NEG 0.2f

// ---------------- CSR build ----------------
__global__ void zero_counts_k(int* __restrict__ c) {
  int i = blockIdx.x * 256 + threadIdx.x;
  if (i < NN) c[i] = 0;
}

__global__ void hist_k(const int* __restrict__ ei, int* __restrict__ counts) {
  int e = blockIdx.x * 256 + threadIdx.x;
  if (e >= ET) return;
  int d = (e < NE) ? ei[NE + e] : (e - NE);
  atomicAdd(&counts[d], 1);
}

__global__ void scan_k(const int* __restrict__ counts, int* __restrict__ offsets,
                       int* __restrict__ cursor) {
  __shared__ int sums[1024];
  int t = threadIdx.x;
  const int CH = (NN + 1023) / 1024;
  int lo = t * CH;
  int hi = min(lo + CH, NN);
  int s = 0;
  for (int i = lo; i < hi; ++i) s += counts[i];
  sums[t] = s;
  __syncthreads();
  for (int off = 1; off < 1024; off <<= 1) {
    int v = sums[t];
    int u = (t >= off) ? sums[t - off] : 0;
    __syncthreads();
    sums[t] = v + u;
    __syncthreads();
  }
  int base = (t == 0) ? 0 : sums[t - 1];
  for (int i = lo; i < hi; ++i) {
    offsets[i] = base;
    cursor[i] = base;
    base += counts[i];
  }
  if (t == 1023) offsets[NN] = sums[1023];
}

__global__ void scatter_k(const int* __restrict__ ei, int* __restrict__ cursor,
                          int* __restrict__ csr) {
  int e = blockIdx.x * 256 + threadIdx.x;
  if (e >= ET) return;
  int s, d;
  if (e < NE) { s = ei[e]; d = ei[NE + e]; } else { s = e - NE; d = s; }
  int pos = atomicAdd(&cursor[d], 1);
  csr[pos] = s;
}

// ---------------- fp32 tiled GEMM: C[M,N] = A[M,K] @ B[K,N] ----------------
__global__ __launch_bounds__(256) void gemm_k(const float* __restrict__ A,
                                              const float* __restrict__ B,
                                              float* __restrict__ C,
                                              int M, int N, int K) {
  const int BM = 64, BN = 64, BK = 32;
  __shared__ float As[BK][BM + 4];
  __shared__ float Bs[BK][BN];
  int bm = blockIdx.y * BM, bn = blockIdx.x * BN;
  int tx = threadIdx.x & 15, ty = threadIdx.x >> 4;
  float acc[4][4] = {};
  for (int k0 = 0; k0 < K; k0 += BK) {
    for (int i = threadIdx.x; i < BM * BK; i += 256) {
      int r = i >> 5, c = i & 31;
      int gr = bm + r;
      As[c][r] = (gr < M) ? A[(size_t)gr * K + k0 + c] : 0.f;
    }
    for (int i = threadIdx.x; i < BK * BN; i += 256) {
      int r = i >> 6, c = i & 63;
      Bs[r][c] = B[(size_t)(k0 + r) * N + bn + c];
    }
    __syncthreads();
#pragma unroll
    for (int k = 0; k < BK; ++k) {
      float a[4], b[4];
#pragma unroll
      for (int i = 0; i < 4; ++i) a[i] = As[k][ty * 4 + i];
#pragma unroll
      for (int j = 0; j < 4; ++j) b[j] = Bs[k][tx * 4 + j];
#pragma unroll
      for (int i = 0; i < 4; ++i)
#pragma unroll
        for (int j = 0; j < 4; ++j) acc[i][j] += a[i] * b[j];
    }
    __syncthreads();
  }
#pragma unroll
  for (int i = 0; i < 4; ++i) {
    int r = bm + ty * 4 + i;
    if (r < M) {
#pragma unroll
      for (int j = 0; j < 4; ++j) C[(size_t)r * N + bn + tx * 4 + j] = acc[i][j];
    }
  }
}

// ---------------- per-(node,head) attention dot products ----------------
template <int H>
__global__ void attdot_k(const float* __restrict__ h, const float* __restrict__ ws,
                         const float* __restrict__ wd, float* __restrict__ as_,
                         float* __restrict__ ad_) {
  int wid = blockIdx.x * 4 + (threadIdx.x >> 6);
  int lane = threadIdx.x & 63;
  if (wid >= NN * H) return;
  int n = wid / H, hd = wid % H;
  float v = h[(size_t)n * (H * HD) + hd * HD + lane];
  float s = v * ws[hd * HD + lane];
  float d = v * wd[hd * HD + lane];
#pragma unroll
  for (int off = 32; off > 0; off >>= 1) {
    s += __shfl_xor(s, off);
    d += __shfl_xor(d, off);
  }
  if (lane == 0) {
    as_[wid] = s;
    ad_[wid] = d;
  }
}

// ---------------- GAT aggregation per destination node ----------------
// block = H*64 threads; thread = (head, channel). Online softmax over the
// node's incoming edge list (CSR), register-resident accumulator.
template <int H, int ACT>
__global__ void gat_agg_k(const int* __restrict__ offsets, const int* __restrict__ csr,
                          const float* __restrict__ h, const float* __restrict__ as_,
                          const float* __restrict__ ad_, const float* __restrict__ bias,
                          float* __restrict__ out) {
  const int C = HD;
  const int T = H * C;
  const int CHK = 256;
  __shared__ float w[CHK][H];
  __shared__ int ss[CHK];
  __shared__ float mrun[H], drun[H], sch[H];
  int n = blockIdx.x;
  int t = threadIdx.x;
  int hd = t >> 6, c = t & 63;
  int beg = offsets[n], end = offsets[n + 1];
  if (t < H) {
    mrun[t] = -1e30f;
    drun[t] = 0.f;
  }
  __syncthreads();
  float acc = 0.f;
  for (int base = beg; base < end; base += CHK) {
    int cnt = min(CHK, end - base);
    for (int i = t; i < cnt; i += T) ss[i] = csr[base + i];
    __syncthreads();
    for (int i = t; i < cnt * H; i += T) {
      int e = i / H, hh = i % H;
      float l = as_[ss[e] * H + hh] + ad_[n * H + hh];
      w[e][hh] = (l > 0.f) ? l : NEG * l;
    }
    __syncthreads();
    if (t < H) {
      float mold = mrun[t];
      float m = mold;
      for (int e = 0; e < cnt; ++e) m = fmaxf(m, w[e][t]);
      float scale = __expf(mold - m);
      float ds = drun[t] * scale;
      for (int e = 0; e < cnt; ++e) {
        float ex = __expf(w[e][t] - m);
        w[e][t] = ex;
        ds += ex;
      }
      mrun[t] = m;
      drun[t] = ds;
      sch[t] = scale;
    }
    __syncthreads();
    acc *= sch[hd];
    for (int e = 0; e < cnt; ++e) acc += w[e][hd] * h[(size_t)ss[e] * T + hd * C + c];
    __syncthreads();
  }
  float res = acc / drun[hd] + bias[hd * C + c];
  if (ACT) res = (res > 0.f) ? res : (__expf(res) - 1.f);
  out[(size_t)n * T + hd * C + c] = res;
}

// ---------------- fused edge MLP: out[e] = relu(p[s]+q[d]+b1).w2 + b2 ------
__global__ void edge_out_k(const int* __restrict__ ei, const float* __restrict__ p,
                           const float* __restrict__ q, const float* __restrict__ mb1,
                           const float* __restrict__ w2, const float* __restrict__ mb2,
                           float* __restrict__ out) {
  int wid = blockIdx.x * 4 + (threadIdx.x >> 6);
  int lane = threadIdx.x & 63;
  if (wid >= NE) return;
  int s = ei[wid], d = ei[NE + wid];
  float v = p[(size_t)s * HD + lane] + q[(size_t)d * HD + lane] + mb1[lane];
  v = fmaxf(v, 0.f);
  float r = v * w2[lane];
#pragma unroll
  for (int off = 32; off > 0; off >>= 1) r += __shfl_xor(r, off);
  if (lane == 0) out[wid] = r + mb2[0];
}

extern "C" void kernel_launch(void* const* d_in, const int* in_sizes, int n_in,
                              void* d_out, int out_size, void* d_ws, size_t ws_size,
                              hipStream_t stream) {
  const float* x = (const float*)d_in[0];
  const int* ei = (const int*)d_in[1];
  const float* W1 = (const float*)d_in[2];
  const float* as1w = (const float*)d_in[3];
  const float* ad1w = (const float*)d_in[4];
  const float* b1 = (const float*)d_in[5];
  const float* W2 = (const float*)d_in[6];
  const float* as2w = (const float*)d_in[7];
  const float* ad2w = (const float*)d_in[8];
  const float* b2 = (const float*)d_in[9];
  const float* mw1 = (const float*)d_in[10];
  const float* mb1 = (const float*)d_in[11];
  const float* mw2 = (const float*)d_in[12];
  const float* mb2 = (const float*)d_in[13];
  float* out = (float*)d_out;

  char* ws = (char*)d_ws;
  size_t o = 0;
  auto alloc = [&](size_t bytes) {
    void* ptr = ws + o;
    o += (bytes + 255) & ~(size_t)255;
    return ptr;
  };
  int* counts = (int*)alloc((size_t)NN * 4);
  int* offsets = (int*)alloc((size_t)(NN + 1) * 4);
  int* cursor = (int*)alloc((size_t)NN * 4);
  int* csr = (int*)alloc((size_t)ET * 4);
  float* h1 = (float*)alloc((size_t)NN * 256 * 4);
  float* a_s1 = (float*)alloc((size_t)NN * 4 * 4);
  float* a_d1 = (float*)alloc((size_t)NN * 4 * 4);
  float* x2 = (float*)alloc((size_t)NN * 256 * 4);
  // reuse h1's region after layer 1 is consumed:
  float* h2 = h1;
  float* y = h1 + (size_t)NN * 64;
  float* p = h1 + (size_t)NN * 128;
  float* q = h1 + (size_t)NN * 192;
  float* a_s2 = a_s1;
  float* a_d2 = a_d1;

  // CSR build (shared by both GAT layers; includes self loops)
  zero_counts_k<<<(NN + 255) / 256, 256, 0, stream>>>(counts);
  hist_k<<<(ET + 255) / 256, 256, 0, stream>>>(ei, counts);
  scan_k<<<1, 1024, 0, stream>>>(counts, offsets, cursor);
  scatter_k<<<(ET + 255) / 256, 256, 0, stream>>>(ei, cursor, csr);

  // Layer 1: h1 = x @ W1 ; attention dots ; aggregate -> x2 = elu(agg + b1)
  dim3 g1(256 / 64, (NN + 63) / 64);
  gemm_k<<<g1, 256, 0, stream>>>(x, W1, h1, NN, 256, 128);
  attdot_k<4><<<NN, 256, 0, stream>>>(h1, as1w, ad1w, a_s1, a_d1);
  gat_agg_k<4, 1><<<NN, 256, 0, stream>>>(offsets, csr, h1, a_s1, a_d1, b1, x2);

  // Layer 2: h2 = x2 @ W2 ; dots ; aggregate -> y = agg + b2
  dim3 g2(1, (NN + 63) / 64);
  gemm_k<<<g2, 256, 0, stream>>>(x2, W2, h2, NN, 64, 256);
  attdot_k<1><<<(NN + 3) / 4, 256, 0, stream>>>(h2, as2w, ad2w, a_s2, a_d2);
  gat_agg_k<1, 0><<<NN, 64, 0, stream>>>(offsets, csr, h2, a_s2, a_d2, b2, y);

  // Edge MLP decomposition: p = y @ mw1[:64], q = y @ mw1[64:]
  dim3 g3(1, (NN + 63) / 64);
  gemm_k<<<g3, 256, 0, stream>>>(y, mw1, p, NN, 64, 64);
  gemm_k<<<g3, 256, 0, stream>>>(y, mw1 + 64 * 64, q, NN, 64, 64);

  // Final per-edge output
  edge_out_k<<<(NE + 3) / 4, 256, 0, stream>>>(ei, p, q, mb1, mw2, mb2, out);
}